// Round 1
// baseline (350.457 us; speedup 1.0000x reference)
//
#include <hip/hip_runtime.h>
#include <math.h>

#define SE_B   32
#define SE_C   256
#define SE_R   16
#define SE_HW  16384   // 128*128

// ---- Kernel 1: global average pool. One block per (b,c) plane. ----
__global__ __launch_bounds__(256) void se_pool_kernel(const float* __restrict__ x,
                                                      float* __restrict__ pooled) {
    const int bc = blockIdx.x;                         // [0, B*C)
    const float4* xv = reinterpret_cast<const float4*>(x + (size_t)bc * SE_HW);
    const int t = threadIdx.x;                         // 256 threads
    float s = 0.f;
#pragma unroll
    for (int k = 0; k < 16; ++k) {                     // 256 thr * 16 * 4 = 16384 floats
        float4 v = xv[t + k * 256];
        s += (v.x + v.y) + (v.z + v.w);
    }
    // wave-64 shuffle reduce
#pragma unroll
    for (int off = 32; off > 0; off >>= 1)
        s += __shfl_down(s, off, 64);
    __shared__ float ws[4];
    const int wave = t >> 6;
    const int lane = t & 63;
    if (lane == 0) ws[wave] = s;
    __syncthreads();
    if (t == 0) {
        float tot = (ws[0] + ws[1]) + (ws[2] + ws[3]);
        pooled[bc] = tot * (1.0f / SE_HW);
    }
}

// ---- Kernel 2: tiny MLP  gate = sigmoid(relu(pooled @ w1^T) @ w2^T). ----
// One block per batch row b; 256 threads.
__global__ __launch_bounds__(256) void se_gate_kernel(const float* __restrict__ pooled,
                                                      const float* __restrict__ w1,
                                                      const float* __restrict__ w2,
                                                      float* __restrict__ gate) {
    const int b = blockIdx.x;                          // [0, B)
    const int t = threadIdx.x;                         // [0, 256)
    __shared__ float p[SE_C];
    __shared__ float h[SE_R];
    p[t] = pooled[b * SE_C + t];
    __syncthreads();
    if (t < SE_R) {
        float acc = 0.f;
        for (int c = 0; c < SE_C; ++c)
            acc = fmaf(p[c], w1[t * SE_C + c], acc);   // w1: [R, C]
        h[t] = fmaxf(acc, 0.f);                        // relu
    }
    __syncthreads();
    float acc = 0.f;
#pragma unroll
    for (int r = 0; r < SE_R; ++r)
        acc = fmaf(h[r], w2[t * SE_R + r], acc);       // w2: [C, R]
    gate[b * SE_C + t] = 1.0f / (1.0f + expf(-acc));   // sigmoid
}

// ---- Kernel 3: out = x * gate[b,c], broadcast over H*W. float4 grid-stride. ----
__global__ __launch_bounds__(256) void se_scale_kernel(const float* __restrict__ x,
                                                       const float* __restrict__ gate,
                                                       float* __restrict__ out,
                                                       long n4) {
    long i = (long)blockIdx.x * blockDim.x + threadIdx.x;
    const long stride = (long)gridDim.x * blockDim.x;
    const float4* xv = reinterpret_cast<const float4*>(x);
    float4* ov = reinterpret_cast<float4*>(out);
    for (; i < n4; i += stride) {
        const float g = gate[i >> 12];                 // (i*4)/16384 — uniform within a float4
        float4 v = xv[i];
        v.x *= g; v.y *= g; v.z *= g; v.w *= g;
        ov[i] = v;
    }
}

extern "C" void kernel_launch(void* const* d_in, const int* in_sizes, int n_in,
                              void* d_out, int out_size, void* d_ws, size_t ws_size,
                              hipStream_t stream) {
    const float* x  = (const float*)d_in[0];   // [32,256,128,128]
    const float* w1 = (const float*)d_in[1];   // [16,256]
    const float* w2 = (const float*)d_in[2];   // [256,16]
    float* out = (float*)d_out;

    float* pooled = (float*)d_ws;                          // 32*256*4 = 32 KiB
    float* gate   = (float*)((char*)d_ws + SE_B * SE_C * sizeof(float)); // next 32 KiB

    // 1. pool: one block per (b,c) plane
    se_pool_kernel<<<SE_B * SE_C, 256, 0, stream>>>(x, pooled);

    // 2. tiny MLP -> gate
    se_gate_kernel<<<SE_B, 256, 0, stream>>>(pooled, w1, w2, gate);

    // 3. scale
    const long n4 = (long)SE_B * SE_C * SE_HW / 4;         // 33,554,432 float4s
    se_scale_kernel<<<2048, 256, 0, stream>>>(x, gate, out, n4);
}

// Round 3
// 272.388 us; speedup vs baseline: 1.2866x; 1.2866x over previous
//
#include <hip/hip_runtime.h>
#include <math.h>

#define SE_B   32
#define SE_C   256
#define SE_R   16
#define SE_HW  16384   // 128*128

typedef float v4f __attribute__((ext_vector_type(4)));   // native vector: NT-store OK

// ---- Kernel 1: global average pool. One block per (b,c) plane, ascending order. ----
__global__ __launch_bounds__(256) void se_pool_kernel(const float* __restrict__ x,
                                                      float* __restrict__ pooled) {
    const int bc = blockIdx.x;                         // [0, B*C)
    const v4f* xv = reinterpret_cast<const v4f*>(x + (size_t)bc * SE_HW);
    const int t = threadIdx.x;                         // 256 threads
    float s = 0.f;
#pragma unroll
    for (int k = 0; k < 16; ++k) {                     // 256 thr * 16 * 4 = 16384 floats
        v4f v = xv[t + k * 256];
        s += (v.x + v.y) + (v.z + v.w);
    }
    // wave-64 shuffle reduce
#pragma unroll
    for (int off = 32; off > 0; off >>= 1)
        s += __shfl_down(s, off, 64);
    __shared__ float ws[4];
    const int wave = t >> 6;
    const int lane = t & 63;
    if (lane == 0) ws[wave] = s;
    __syncthreads();
    if (t == 0) {
        float tot = (ws[0] + ws[1]) + (ws[2] + ws[3]);
        pooled[bc] = tot * (1.0f / SE_HW);
    }
}

// ---- Kernel 2: tiny MLP  gate = sigmoid(relu(pooled @ w1^T) @ w2^T). ----
__global__ __launch_bounds__(256) void se_gate_kernel(const float* __restrict__ pooled,
                                                      const float* __restrict__ w1,
                                                      const float* __restrict__ w2,
                                                      float* __restrict__ gate) {
    const int b = blockIdx.x;                          // [0, B)
    const int t = threadIdx.x;                         // [0, 256)
    __shared__ float p[SE_C];
    __shared__ float h[SE_R];
    p[t] = pooled[b * SE_C + t];
    __syncthreads();
    if (t < SE_R) {
        float acc = 0.f;
        for (int c = 0; c < SE_C; ++c)
            acc = fmaf(p[c], w1[t * SE_C + c], acc);   // w1: [R, C]
        h[t] = fmaxf(acc, 0.f);                        // relu
    }
    __syncthreads();
    float acc = 0.f;
#pragma unroll
    for (int r = 0; r < SE_R; ++r)
        acc = fmaf(h[r], w2[t * SE_R + r], acc);       // w2: [C, R]
    gate[b * SE_C + t] = 1.0f / (1.0f + expf(-acc));   // sigmoid
}

// ---- Kernel 3: out = x * gate[b,c]. Blocks traverse chunks in DESCENDING
// address order so the first reads hit the L3 residue the pool pass left
// behind (tail of x), and the last reads leave the head of x resident for
// the next replay's ascending pool pass. NT stores keep out of L2/L3. ----
__global__ __launch_bounds__(256) void se_scale_kernel(const float* __restrict__ x,
                                                       const float* __restrict__ gate,
                                                       float* __restrict__ out) {
    // grid = 2048 blocks; each handles 4 full (b,c) planes = 16384 float4s.
    const int chunk = gridDim.x - 1 - blockIdx.x;      // reverse mapping
    const long base_plane = (long)chunk * 4;           // first plane of this chunk
    const v4f* xv = reinterpret_cast<const v4f*>(x);
    v4f* ov = reinterpret_cast<v4f*>(out);
    const int t = threadIdx.x;
#pragma unroll
    for (int p = 3; p >= 0; --p) {                     // descending within chunk too
        const long plane = base_plane + p;
        const float g = gate[plane];                   // uniform for whole plane
        const long pb = plane * (SE_HW / 4);           // 4096 float4s per plane
#pragma unroll
        for (int k = 15; k >= 0; --k) {
            const long i = pb + (long)k * 256 + t;
            v4f v = xv[i];
            v *= g;
            __builtin_nontemporal_store(v, &ov[i]);
        }
    }
}

extern "C" void kernel_launch(void* const* d_in, const int* in_sizes, int n_in,
                              void* d_out, int out_size, void* d_ws, size_t ws_size,
                              hipStream_t stream) {
    const float* x  = (const float*)d_in[0];   // [32,256,128,128]
    const float* w1 = (const float*)d_in[1];   // [16,256]
    const float* w2 = (const float*)d_in[2];   // [256,16]
    float* out = (float*)d_out;

    float* pooled = (float*)d_ws;                          // 32*256*4 = 32 KiB
    float* gate   = (float*)((char*)d_ws + SE_B * SE_C * sizeof(float)); // next 32 KiB

    // 1. pool: one block per (b,c) plane (ascending)
    se_pool_kernel<<<SE_B * SE_C, 256, 0, stream>>>(x, pooled);

    // 2. tiny MLP -> gate
    se_gate_kernel<<<SE_B, 256, 0, stream>>>(pooled, w1, w2, gate);

    // 3. scale (descending, NT stores); 2048 blocks * 4 planes = 8192 planes
    se_scale_kernel<<<2048, 256, 0, stream>>>(x, gate, out);
}